// Round 11
// baseline (610.946 us; speedup 1.0000x reference)
//
#include <hip/hip_runtime.h>

#define ALPHA 0.2f

constexpr int IN  = 64;
constexpr int EIN = 32;
constexpr int H   = 4;
constexpr int D   = 16;
constexpr int HD  = 64;
constexpr int MAXDEG = 96;   // deg ~ Poisson(32); P(>96) < 1e-20

typedef float f32x4 __attribute__((ext_vector_type(4)));   // clang vector: ok for nontemporal builtins

// 16B ELL record: eid, src, 4 scores as bf16x2 pairs. One dwordx4 store.
struct alignas(16) Rec { int eid; int srcn; unsigned s01; unsigned s23; };

__device__ inline unsigned pack_bf16x2(float lo, float hi) {
  unsigned a = __float_as_uint(lo), b = __float_as_uint(hi);
  a = (a + 0x7FFFu + ((a >> 16) & 1u)) >> 16;
  b = (b + 0x7FFFu + ((b >> 16) & 1u)) >> 16;
  return a | (b << 16);
}

__device__ inline float unpack_sc(unsigned s01, unsigned s23, int h) {
  unsigned w = (h & 2) ? s23 : s01;
  unsigned half = (h & 1) ? (w >> 16) : (w & 0xFFFFu);
  return __uint_as_float(half << 16);
}

// ---------------------------------------------------------------------------
// Node transform, tiled-GEMM style (no per-k shuffles).
// ---------------------------------------------------------------------------
__global__ __launch_bounds__(256) void node_v2_kernel(
    const float* __restrict__ x, const float* __restrict__ W,
    const float* __restrict__ b, const float* __restrict__ attn_l,
    const float* __restrict__ attn_r,
    float* __restrict__ ft, float* __restrict__ a1, float* __restrict__ a2,
    int N) {
  __shared__ float xs[64][68];   // A: x^T [k][node]; B: ft [node][col]
  __shared__ float Ws[64][64];   // W [k][c]
  int tid = threadIdx.x;
  int nbase = blockIdx.x * 64;
  for (int i = tid; i < 1024; i += 256)
    ((float4*)Ws)[i] = ((const float4*)W)[i];
  for (int i = tid; i < 1024; i += 256) {
    int node = i >> 4;
    int k4 = (i & 15) * 4;
    int gn = nbase + node;
    f32x4 v = {0.f, 0.f, 0.f, 0.f};
    if (gn < N) v = __builtin_nontemporal_load(((const f32x4*)(x + (size_t)gn * IN)) + (i & 15));
    xs[k4 + 0][node] = v.x; xs[k4 + 1][node] = v.y;
    xs[k4 + 2][node] = v.z; xs[k4 + 3][node] = v.w;
  }
  __syncthreads();
  int cg = tid & 15, ng = tid >> 4;
  float4 bv = ((const float4*)b)[cg];
  float acc[4][4];
  #pragma unroll
  for (int ni = 0; ni < 4; ++ni) {
    acc[ni][0] = bv.x; acc[ni][1] = bv.y; acc[ni][2] = bv.z; acc[ni][3] = bv.w;
  }
  #pragma unroll 8
  for (int k = 0; k < 64; ++k) {
    float4 wv = *(const float4*)&Ws[k][cg * 4];
    float4 xv = *(const float4*)&xs[k][ng * 4];
    const float* wp = &wv.x;
    const float* xp = &xv.x;
    #pragma unroll
    for (int ni = 0; ni < 4; ++ni)
      #pragma unroll
      for (int c = 0; c < 4; ++c)
        acc[ni][c] += xp[ni] * wp[c];
  }
  __syncthreads();
  #pragma unroll
  for (int ni = 0; ni < 4; ++ni) {
    int node = ng * 4 + ni;
    float4 o = make_float4(acc[ni][0], acc[ni][1], acc[ni][2], acc[ni][3]);
    *(float4*)&xs[node][cg * 4] = o;
    int gn = nbase + node;
    if (gn < N) ((float4*)(ft + (size_t)gn * HD))[cg] = o;
  }
  __syncthreads();
  int node = tid >> 2, h = tid & 3;
  int gn = nbase + node;
  if (gn < N) {
    float p1 = 0.f, p2 = 0.f;
    #pragma unroll
    for (int d4 = 0; d4 < 4; ++d4) {
      float4 fv = *(const float4*)&xs[node][h * 16 + d4 * 4];
      float4 lv = ((const float4*)attn_l)[h * 4 + d4];
      float4 rv = ((const float4*)attn_r)[h * 4 + d4];
      p1 += fv.x * lv.x + fv.y * lv.y + fv.z * lv.z + fv.w * lv.w;
      p2 += fv.x * rv.x + fv.y * rv.y + fv.z * rv.z + fv.w * rv.w;
    }
    a1[(size_t)gn * H + h] = p1;
    a2[(size_t)gn * H + h] = p2;
  }
}

// ---------------------------------------------------------------------------
// Edge kernel: TWO edges per thread (independent atomic->store chains).
// e / src / dst are non-temporal (read-once streams) so the ELL scatter
// region stays cache-resident and RMW is absorbed in L2/L3.
// ---------------------------------------------------------------------------
__global__ __launch_bounds__(256) void edge_ell_kernel(
    const float* __restrict__ e, const int* __restrict__ src,
    const int* __restrict__ dst, const float* __restrict__ attn_e,
    const float* __restrict__ a1, const float* __restrict__ a2,
    int* __restrict__ cnt, Rec* __restrict__ ell, int E) {
  __shared__ float Ael[EIN * H];
  int tid = threadIdx.x;
  if (tid < EIN * H) Ael[tid] = attn_e[tid];
  __syncthreads();
  int base = blockIdx.x * 512;
  #pragma unroll
  for (int half = 0; half < 2; ++half) {
    int i = base + half * 256 + tid;
    if (i >= E) continue;
    int d = __builtin_nontemporal_load(dst + i);
    int s = __builtin_nontemporal_load(src + i);
    const f32x4* e4 = (const f32x4*)(e + (size_t)i * EIN);
    float a3h[H] = {0.f, 0.f, 0.f, 0.f};
    #pragma unroll
    for (int j = 0; j < 8; ++j) {
      f32x4 v = __builtin_nontemporal_load(e4 + j);
      #pragma unroll
      for (int t = 0; t < 4; ++t) {
        float ek = v[t];
        int k = j * 4 + t;
        #pragma unroll
        for (int h = 0; h < H; ++h) a3h[h] += ek * Ael[k * H + h];
      }
    }
    float4 av1 = ((const float4*)a1)[s];   // cached: a1/a2 reused across edges
    float4 av2 = ((const float4*)a2)[d];
    const float* p1 = &av1.x;
    const float* p2 = &av2.x;
    float o[H];
    #pragma unroll
    for (int h = 0; h < H; ++h) {
      float a = p1[h] + p2[h] + a3h[h];
      a = a > 0.f ? a : ALPHA * a;
      o[h] = __expf(a);   // logits bounded; softmax ratio cancels the shift
    }
    int slot = atomicAdd(&cnt[d], 1);
    if (slot < MAXDEG) {
      Rec r;
      r.eid = i; r.srcn = s;
      r.s01 = pack_bf16x2(o[0], o[1]);
      r.s23 = pack_bf16x2(o[2], o[3]);
      *(Rec*)(ell + (size_t)d * MAXDEG + slot) = r;   // one 16B store
    }
  }
}

// ---------------------------------------------------------------------------
// Aggregate: one wave per node over its ELL row (sequential 16B records).
// Two gathers per edge: e row (nt, 128B HBM) and ft row (cached, L2/L3).
// Epilogue: out = acc/z + esum@We + deg*be.
// ---------------------------------------------------------------------------
__global__ __launch_bounds__(256) void agg_ell_kernel(
    const float* __restrict__ e, const float* __restrict__ ft,
    const int* __restrict__ cnt, const Rec* __restrict__ ell,
    const float* __restrict__ We, const float* __restrict__ be,
    float* __restrict__ out, int N) {
  __shared__ float Wel[EIN * HD];   // 8 KB
  __shared__ float bel[HD];
  int tid = threadIdx.x;
  for (int i = tid; i < EIN * HD; i += 256) Wel[i] = We[i];
  if (tid < HD) bel[tid] = be[tid];
  __syncthreads();
  int lane = tid & 63, wid = tid >> 6;
  int n = blockIdx.x * 4 + wid;
  if (n >= N) return;
  int deg = cnt[n];
  deg = deg < MAXDEG ? deg : MAXDEG;
  const int4* row = (const int4*)(ell + (size_t)n * MAXDEG);
  int h  = lane >> 4;
  int ke = lane & 31;
  float acc = 0.f, z = 0.f, esum = 0.f;
  int i = 0;
  for (; i + 8 <= deg; i += 8) {
    int4 rec[8];
    float scv[8], ev[8], fv[8];
    #pragma unroll
    for (int u = 0; u < 8; ++u) rec[u] = row[i + u];
    #pragma unroll
    for (int u = 0; u < 8; ++u)
      ev[u] = __builtin_nontemporal_load(e + (size_t)rec[u].x * EIN + ke);
    #pragma unroll
    for (int u = 0; u < 8; ++u) fv[u] = ft[(size_t)rec[u].y * HD + lane];
    #pragma unroll
    for (int u = 0; u < 8; ++u)
      scv[u] = unpack_sc((unsigned)rec[u].z, (unsigned)rec[u].w, h);
    #pragma unroll
    for (int u = 0; u < 8; ++u) {
      acc += scv[u] * fv[u];
      z += scv[u];
      esum += ev[u];
    }
  }
  for (; i < deg; ++i) {
    int4 r = row[i];
    float sc = unpack_sc((unsigned)r.z, (unsigned)r.w, h);
    float ev = __builtin_nontemporal_load(e + (size_t)r.x * EIN + ke);
    float fv = ft[(size_t)r.y * HD + lane];
    acc += sc * fv;
    z += sc;
    esum += ev;
  }
  float sacc = 0.f;
  #pragma unroll
  for (int k = 0; k < EIN; ++k) {
    float ekk = __shfl(esum, k);
    sacc += ekk * Wel[k * HD + lane];
  }
  float agg = (z > 0.f) ? acc / z : 0.f;
  out[(size_t)n * HD + lane] = agg + sacc + (float)deg * bel[lane];
}

// ---------------------------------------------------------------------------
extern "C" void kernel_launch(void* const* d_in, const int* in_sizes, int n_in,
                              void* d_out, int out_size, void* d_ws, size_t ws_size,
                              hipStream_t stream) {
  const float* x      = (const float*)d_in[0];
  const float* e      = (const float*)d_in[1];
  const int*   src    = (const int*)d_in[2];
  const int*   dst    = (const int*)d_in[3];
  const float* W      = (const float*)d_in[4];
  const float* b      = (const float*)d_in[5];
  const float* We     = (const float*)d_in[6];
  const float* be     = (const float*)d_in[7];
  const float* attn_l = (const float*)d_in[8];
  const float* attn_r = (const float*)d_in[9];
  const float* attn_e = (const float*)d_in[10];
  float* out = (float*)d_out;
  int N = in_sizes[0] / IN;
  int E = in_sizes[1] / EIN;

  // workspace carve-up (16B-aligned); ~92 MB total
  char* w = (char*)d_ws;
  float* ft  = (float*)w; w += (size_t)N * HD * 4;    // 12.8 MB
  float* a1  = (float*)w; w += (size_t)N * H * 4;     // 0.8 MB
  float* a2  = (float*)w; w += (size_t)N * H * 4;     // 0.8 MB
  int*   cnt = (int*)w;   w += (size_t)N * 4;         // 0.2 MB
  Rec*   ell = (Rec*)w;   w += (size_t)N * MAXDEG * sizeof(Rec);  // 76.8 MB

  (void)hipMemsetAsync(cnt, 0, (size_t)N * sizeof(int), stream);

  node_v2_kernel<<<(N + 63) / 64, 256, 0, stream>>>(
      x, W, b, attn_l, attn_r, ft, a1, a2, N);
  edge_ell_kernel<<<(E + 511) / 512, 256, 0, stream>>>(
      e, src, dst, attn_e, a1, a2, cnt, ell, E);
  agg_ell_kernel<<<(N + 3) / 4, 256, 0, stream>>>(
      e, ft, cnt, ell, We, be, out, N);
}

// Round 12
// 543.164 us; speedup vs baseline: 1.1248x; 1.1248x over previous
//
#include <hip/hip_runtime.h>

#define ALPHA 0.2f

constexpr int IN  = 64;
constexpr int EIN = 32;
constexpr int H   = 4;
constexpr int D   = 16;
constexpr int HD  = 64;
constexpr int MAXDEG = 96;   // deg ~ Poisson(32); P(>96) < 1e-20

typedef float f32x4 __attribute__((ext_vector_type(4)));

// DPP row_ror:N add (16-lane row rotate-reduce, VALU pipe -- no DS)
template <int CTRL>
__device__ inline float dpp_add(float v) {
  int r = __builtin_amdgcn_update_dpp(0, __float_as_int(v), CTRL, 0xF, 0xF, false);
  return v + __int_as_float(r);
}
__device__ inline float red16(float v) {
  v = dpp_add<0x121>(v);   // row_ror:1
  v = dpp_add<0x122>(v);   // row_ror:2
  v = dpp_add<0x124>(v);   // row_ror:4
  v = dpp_add<0x128>(v);   // row_ror:8
  return v;                // every lane in the 16-row holds the row sum
}
__device__ inline float bpermf(int byte_addr, float v) {
  return __int_as_float(__builtin_amdgcn_ds_bpermute(byte_addr, __float_as_int(v)));
}

// ---------------------------------------------------------------------------
// Node transform, tiled-GEMM style (unchanged from round 8; passed twice).
// ---------------------------------------------------------------------------
__global__ __launch_bounds__(256) void node_v2_kernel(
    const float* __restrict__ x, const float* __restrict__ W,
    const float* __restrict__ b, const float* __restrict__ attn_l,
    const float* __restrict__ attn_r,
    float* __restrict__ ft, float* __restrict__ a1, float* __restrict__ a2,
    int N) {
  __shared__ float xs[64][68];
  __shared__ float Ws[64][64];
  int tid = threadIdx.x;
  int nbase = blockIdx.x * 64;
  for (int i = tid; i < 1024; i += 256)
    ((float4*)Ws)[i] = ((const float4*)W)[i];
  for (int i = tid; i < 1024; i += 256) {
    int node = i >> 4;
    int k4 = (i & 15) * 4;
    int gn = nbase + node;
    f32x4 v = {0.f, 0.f, 0.f, 0.f};
    if (gn < N) v = *(((const f32x4*)(x + (size_t)gn * IN)) + (i & 15));
    xs[k4 + 0][node] = v.x; xs[k4 + 1][node] = v.y;
    xs[k4 + 2][node] = v.z; xs[k4 + 3][node] = v.w;
  }
  __syncthreads();
  int cg = tid & 15, ng = tid >> 4;
  float4 bv = ((const float4*)b)[cg];
  float acc[4][4];
  #pragma unroll
  for (int ni = 0; ni < 4; ++ni) {
    acc[ni][0] = bv.x; acc[ni][1] = bv.y; acc[ni][2] = bv.z; acc[ni][3] = bv.w;
  }
  #pragma unroll 8
  for (int k = 0; k < 64; ++k) {
    float4 wv = *(const float4*)&Ws[k][cg * 4];
    float4 xv = *(const float4*)&xs[k][ng * 4];
    const float* wp = &wv.x;
    const float* xp = &xv.x;
    #pragma unroll
    for (int ni = 0; ni < 4; ++ni)
      #pragma unroll
      for (int c = 0; c < 4; ++c)
        acc[ni][c] += xp[ni] * wp[c];
  }
  __syncthreads();
  #pragma unroll
  for (int ni = 0; ni < 4; ++ni) {
    int node = ng * 4 + ni;
    float4 o = make_float4(acc[ni][0], acc[ni][1], acc[ni][2], acc[ni][3]);
    *(float4*)&xs[node][cg * 4] = o;
    int gn = nbase + node;
    if (gn < N) ((float4*)(ft + (size_t)gn * HD))[cg] = o;
  }
  __syncthreads();
  int node = tid >> 2, h = tid & 3;
  int gn = nbase + node;
  if (gn < N) {
    float p1 = 0.f, p2 = 0.f;
    #pragma unroll
    for (int d4 = 0; d4 < 4; ++d4) {
      float4 fv = *(const float4*)&xs[node][h * 16 + d4 * 4];
      float4 lv = ((const float4*)attn_l)[h * 4 + d4];
      float4 rv = ((const float4*)attn_r)[h * 4 + d4];
      p1 += fv.x * lv.x + fv.y * lv.y + fv.z * lv.z + fv.w * lv.w;
      p2 += fv.x * rv.x + fv.y * rv.y + fv.z * rv.z + fv.w * rv.w;
    }
    a1[(size_t)gn * H + h] = p1;
    a2[(size_t)gn * H + h] = p2;
  }
}

// ---------------------------------------------------------------------------
// Fill: ELL {eid, src} only (8B scatter). 4 independent chains per thread.
// No e read here at all -- e is touched exactly once, in the fused agg.
// ---------------------------------------------------------------------------
__global__ __launch_bounds__(256) void fill_kernel(
    const int* __restrict__ src, const int* __restrict__ dst,
    int* __restrict__ cnt, int2* __restrict__ ell, int E) {
  int base = blockIdx.x * 1024 + threadIdx.x;
  #pragma unroll
  for (int u = 0; u < 4; ++u) {
    int i = base + u * 256;
    if (i < E) {
      int d = dst[i], s = src[i];
      int slot = atomicAdd(&cnt[d], 1);
      if (slot < MAXDEG) ell[(size_t)d * MAXDEG + slot] = make_int2(i, s);
    }
  }
}

// ---------------------------------------------------------------------------
// Fused aggregate: one wave per node; 4 edges per phase (16 lanes each).
// Per phase: 4 rec loads (wave-uniform) -> 2 e-loads (4x64B lines each,
// 100% utilization) -> a3 for 4 heads via DPP row_ror reduce (VALU, no DS)
// -> leaky+exp -> 4 ds_bpermute to the accumulate layout -> 4 ft-row FMAs.
// esum accumulates from the already-loaded ev registers.
// Epilogue: out = acc/z + esum@We + deg*be.
// ---------------------------------------------------------------------------
__global__ __launch_bounds__(256) void agg_fused_kernel(
    const float* __restrict__ e, const float* __restrict__ ft,
    const float* __restrict__ a1, const float* __restrict__ a2,
    const float* __restrict__ attn_e,
    const int* __restrict__ cnt, const int2* __restrict__ ell,
    const float* __restrict__ We, const float* __restrict__ be,
    float* __restrict__ out, int N) {
  __shared__ float Wel[EIN * HD];   // 8 KB
  __shared__ float bel[HD];
  int tid = threadIdx.x;
  for (int i = tid; i < EIN * HD; i += 256) Wel[i] = We[i];
  if (tid < HD) bel[tid] = be[tid];
  __syncthreads();
  int lane = tid & 63, wid = tid >> 6;
  int n = blockIdx.x * 4 + wid;
  if (n >= N) return;
  int grp = lane >> 4;        // which of 4 edges in the phase
  int kk  = lane & 15;        // k-slot within the edge
  int hsel = kk & 3;          // head this lane scores
  int deg = cnt[n];
  deg = deg < MAXDEG ? deg : MAXDEG;
  const int2* row = ell + (size_t)n * MAXDEG;
  // hoisted per-lane constants
  float4 aeA = ((const float4*)attn_e)[kk];        // attn_e[kk][0..3]
  float4 aeB = ((const float4*)attn_e)[kk + 16];   // attn_e[kk+16][0..3]
  float a2sel = a2[(size_t)n * H + hsel];
  int bp0 = (0 * 16 + grp) * 4, bp1 = (1 * 16 + grp) * 4;
  int bp2 = (2 * 16 + grp) * 4, bp3 = (3 * 16 + grp) * 4;
  float acc = 0.f, z = 0.f, es0 = 0.f, es1 = 0.f;
  for (int i = 0; i < deg; i += 4) {
    int rem = deg - i;
    int i1 = rem > 1 ? i + 1 : i;
    int i2 = rem > 2 ? i + 2 : i;
    int i3 = rem > 3 ? i + 3 : i;
    int2 r0 = row[i], r1 = row[i1], r2 = row[i2], r3 = row[i3];
    int eidu = (grp & 2) ? ((grp & 1) ? r3.x : r2.x) : ((grp & 1) ? r1.x : r0.x);
    int srcu = (grp & 2) ? ((grp & 1) ? r3.y : r2.y) : ((grp & 1) ? r1.y : r0.y);
    const float* erow = e + (size_t)eidu * EIN;
    float ev0 = erow[kk];
    float ev1 = erow[kk + 16];
    // a3 for 4 heads: per-lane partials, then 16-lane DPP reduce
    float p0 = ev0 * aeA.x + ev1 * aeB.x;
    float p1 = ev0 * aeA.y + ev1 * aeB.y;
    float p2 = ev0 * aeA.z + ev1 * aeB.z;
    float p3 = ev0 * aeA.w + ev1 * aeB.w;
    p0 = red16(p0); p1 = red16(p1); p2 = red16(p2); p3 = red16(p3);
    float psel = (hsel & 2) ? ((hsel & 1) ? p3 : p2) : ((hsel & 1) ? p1 : p0);
    float a1v = a1[(size_t)srcu * H + hsel];
    float lg = a1v + a2sel + psel;
    lg = lg > 0.f ? lg : ALPHA * lg;
    float sc = __expf(lg);    // logits bounded; softmax ratio cancels the shift
    // redistribute: vs_u(lane) = score of edge u, head (lane>>4)
    float vs0 = bpermf(bp0, sc);
    float vs1 = bpermf(bp1, sc);
    float vs2 = bpermf(bp2, sc);
    float vs3 = bpermf(bp3, sc);
    if (rem < 4) {            // wave-uniform tail masking
      vs1 = rem > 1 ? vs1 : 0.f;
      vs2 = rem > 2 ? vs2 : 0.f;
      vs3 = rem > 3 ? vs3 : 0.f;
    }
    float ft0 = ft[(size_t)r0.y * HD + lane];
    float ft1 = ft[(size_t)r1.y * HD + lane];
    float ft2 = ft[(size_t)r2.y * HD + lane];
    float ft3 = ft[(size_t)r3.y * HD + lane];
    acc += vs0 * ft0; acc += vs1 * ft1; acc += vs2 * ft2; acc += vs3 * ft3;
    z += vs0 + vs1 + vs2 + vs3;
    bool gvalid = grp < rem;
    es0 += gvalid ? ev0 : 0.f;
    es1 += gvalid ? ev1 : 0.f;
  }
  // cross-group esum reduce: sum lanes {L, L^16, L^32, L^48}
  float t0 = es0 + bpermf((lane ^ 16) << 2, es0);
  t0 = t0 + bpermf((lane ^ 32) << 2, t0);
  float t1 = es1 + bpermf((lane ^ 16) << 2, es1);
  t1 = t1 + bpermf((lane ^ 32) << 2, t1);
  float esum = (lane & 16) ? t1 : t0;   // lanes 0..31 hold esum[lane&31]
  float sacc = 0.f;
  #pragma unroll
  for (int k = 0; k < EIN; ++k) {
    float ekk = __shfl(esum, k);
    sacc += ekk * Wel[k * HD + lane];
  }
  float agg = (z > 0.f) ? acc / z : 0.f;
  out[(size_t)n * HD + lane] = agg + sacc + (float)deg * bel[lane];
}

// ---------------------------------------------------------------------------
extern "C" void kernel_launch(void* const* d_in, const int* in_sizes, int n_in,
                              void* d_out, int out_size, void* d_ws, size_t ws_size,
                              hipStream_t stream) {
  const float* x      = (const float*)d_in[0];
  const float* e      = (const float*)d_in[1];
  const int*   src    = (const int*)d_in[2];
  const int*   dst    = (const int*)d_in[3];
  const float* W      = (const float*)d_in[4];
  const float* b      = (const float*)d_in[5];
  const float* We     = (const float*)d_in[6];
  const float* be     = (const float*)d_in[7];
  const float* attn_l = (const float*)d_in[8];
  const float* attn_r = (const float*)d_in[9];
  const float* attn_e = (const float*)d_in[10];
  float* out = (float*)d_out;
  int N = in_sizes[0] / IN;
  int E = in_sizes[1] / EIN;

  // workspace carve-up (16B-aligned); ~53 MB total
  char* w = (char*)d_ws;
  float* ft  = (float*)w; w += (size_t)N * HD * 4;    // 12.8 MB
  float* a1  = (float*)w; w += (size_t)N * H * 4;     // 0.8 MB
  float* a2  = (float*)w; w += (size_t)N * H * 4;     // 0.8 MB
  int*   cnt = (int*)w;   w += (size_t)N * 4;         // 0.2 MB
  int2*  ell = (int2*)w;  w += (size_t)N * MAXDEG * 8; // 38.4 MB

  (void)hipMemsetAsync(cnt, 0, (size_t)N * sizeof(int), stream);

  node_v2_kernel<<<(N + 63) / 64, 256, 0, stream>>>(
      x, W, b, attn_l, attn_r, ft, a1, a2, N);
  fill_kernel<<<(E + 1023) / 1024, 256, 0, stream>>>(src, dst, cnt, ell, E);
  agg_fused_kernel<<<(N + 3) / 4, 256, 0, stream>>>(
      e, ft, a1, a2, attn_e, cnt, ell, We, be, out, N);
}